// Round 4
// baseline (3561.758 us; speedup 1.0000x reference)
//
#include <hip/hip_runtime.h>
#include <math.h>

// ---------------------------------------------------------------------------
// MixedChunkAttention — fp32 exact baseline (round 4 = round 2 resubmit;
// GPU was unavailable all prior rounds, this code has never executed).
// B=4 N=4096 D=1024 H=2048 2H=4096 QD=128 G=256 -> M=16384 rows.
// ws usage: vv + gate = 256 MiB exactly (accb written in-place over gate).
// Small scratch (qp,kp,mean,rstd,bias,linkv) lives in d_out's out region,
// which k_gemm_out fully overwrites at the end.
// ---------------------------------------------------------------------------

static __device__ __forceinline__ float silu_f(float x) {
  return x / (1.f + expf(-x));
}

// ---------------- K0: zero linkv (atomics target) --------------------------
__global__ __launch_bounds__(256) void k_zero(float4* __restrict__ p) {
  p[(size_t)blockIdx.x * 256 + threadIdx.x] = make_float4(0.f, 0.f, 0.f, 0.f);
}

// ---------------- K1: layernorm row stats (mean, rstd) ---------------------
__global__ __launch_bounds__(256) void k_ln_stats(
    const float* __restrict__ v, float* __restrict__ mean,
    float* __restrict__ rstd) {
  int wid = threadIdx.x >> 6, lane = threadIdx.x & 63;
  int row = (blockIdx.x << 2) + wid;
  const float4* p = (const float4*)(v + (size_t)row * 1024);
  float s = 0.f, sq = 0.f;
#pragma unroll
  for (int i = 0; i < 4; ++i) {
    float4 x = p[lane + (i << 6)];
    s += (x.x + x.y) + (x.z + x.w);
    sq += x.x * x.x + x.y * x.y + x.z * x.z + x.w * x.w;
  }
#pragma unroll
  for (int m = 32; m; m >>= 1) {
    s += __shfl_xor(s, m);
    sq += __shfl_xor(sq, m);
  }
  if (lane == 0) {
    float mu = s * (1.f / 1024.f);
    float var = sq * (1.f / 1024.f) - mu * mu;
    mean[row] = mu;
    rstd[row] = rsqrtf(var + 1e-5f);
  }
}

// ---------------- K2: T5 relative position bias table ----------------------
// bucket: ret=(j>i)*16; an=|i-j|; an<8 ? an : min(33-clz(an*an),15)
// (33-clz(n^2) == 8 + floor(2*log2(n/8)) exactly; verified the fp32 ref
// rounds the same way at n=16/32/64/128.)
__global__ __launch_bounds__(256) void k_bias(const float* __restrict__ rel,
                                              float* __restrict__ bias) {
  int i = blockIdx.x, j = threadIdx.x;
  int n = i - j;  // n = -(k_pos - q_pos)
  int ret = (n < 0) ? 16 : 0;
  int an = n < 0 ? -n : n;
  int bucket;
  if (an < 8)
    bucket = ret + an;
  else {
    int vl = 33 - __clz(an * an);
    bucket = ret + (vl < 15 ? vl : 15);
  }
  bias[(i << 8) + j] = rel[bucket] * 11.313708498984761f;  // *sqrt(128)
}

// ---------------- K3: hid = silu(LN(v) @ w_hid + b_hid), split vv|gate -----
__global__ __launch_bounds__(256) void k_gemm_hid(
    const float* __restrict__ v, const float* __restrict__ mean,
    const float* __restrict__ rstd, const float* __restrict__ ln_g,
    const float* __restrict__ ln_b, const float* __restrict__ w_hid,
    const float* __restrict__ b_hid, float* __restrict__ vv,
    float* __restrict__ gate) {
  __shared__ float As[16][132];
  __shared__ float Bs[16][132];
  const int tid = threadIdx.x;
  const int tx = tid & 15, ty = tid >> 4;
  const int m0 = blockIdx.y << 7, n0 = blockIdx.x << 7;
  float acc[8][8] = {};
  for (int k0 = 0; k0 < 1024; k0 += 16) {
    int f = tid;
#pragma unroll
    for (int it = 0; it < 2; ++it, f += 256) {
      int row = f >> 2, kq = (f & 3) << 2;
      int gr = m0 + row;
      float4 x = *(const float4*)(v + (size_t)gr * 1024 + k0 + kq);
      float mu = mean[gr], rs = rstd[gr];
      As[kq + 0][row] = (x.x - mu) * rs * ln_g[k0 + kq + 0] + ln_b[k0 + kq + 0];
      As[kq + 1][row] = (x.y - mu) * rs * ln_g[k0 + kq + 1] + ln_b[k0 + kq + 1];
      As[kq + 2][row] = (x.z - mu) * rs * ln_g[k0 + kq + 2] + ln_b[k0 + kq + 2];
      As[kq + 3][row] = (x.w - mu) * rs * ln_g[k0 + kq + 3] + ln_b[k0 + kq + 3];
    }
    f = tid;
#pragma unroll
    for (int it = 0; it < 2; ++it, f += 256) {
      int kk = f >> 5, nq = (f & 31) << 2;
      *(float4*)&Bs[kk][nq] =
          *(const float4*)(w_hid + (size_t)(k0 + kk) * 4096 + n0 + nq);
    }
    __syncthreads();
#pragma unroll
    for (int kk = 0; kk < 16; ++kk) {
      float a[8], b[8];
      *(float4*)&a[0] = *(const float4*)&As[kk][ty << 3];
      *(float4*)&a[4] = *(const float4*)&As[kk][(ty << 3) + 4];
      *(float4*)&b[0] = *(const float4*)&Bs[kk][tx << 3];
      *(float4*)&b[4] = *(const float4*)&Bs[kk][(tx << 3) + 4];
#pragma unroll
      for (int i = 0; i < 8; ++i)
#pragma unroll
        for (int j = 0; j < 8; ++j) acc[i][j] = fmaf(a[i], b[j], acc[i][j]);
    }
    __syncthreads();
  }
  const bool isv = n0 < 2048;
  float* dst = isv ? vv : gate;
  const int nb = isv ? n0 : n0 - 2048;
#pragma unroll
  for (int i = 0; i < 8; ++i) {
    int r = m0 + (ty << 3) + i;
    float* drow = dst + (size_t)r * 2048 + nb + (tx << 3);
#pragma unroll
    for (int j = 0; j < 8; ++j) {
      float x = acc[i][j] + b_hid[n0 + (tx << 3) + j];
      drow[j] = silu_f(x);
    }
  }
}

// ---------------- K4: qp = silu(q@w_q+b_q), kp = silu(k@w_k+b_k) -----------
__global__ __launch_bounds__(256) void k_proj(
    const float* __restrict__ q, const float* __restrict__ k,
    const float* __restrict__ w_q, const float* __restrict__ b_q,
    const float* __restrict__ w_k, const float* __restrict__ b_k,
    float* __restrict__ qp, float* __restrict__ kp) {
  __shared__ float As[16][68];
  __shared__ float Bs[16][132];
  const int tid = threadIdx.x;
  const int tx = tid & 15, ty = tid >> 4;
  const int m0 = blockIdx.x << 6;
  const bool isq = blockIdx.y == 0;
  const float* src = isq ? q : k;
  const float* w = isq ? w_q : w_k;
  const float* bv = isq ? b_q : b_k;
  float* dst = isq ? qp : kp;
  float acc[4][8] = {};
  for (int k0 = 0; k0 < 1024; k0 += 16) {
    {
      int row = tid >> 2, kq = (tid & 3) << 2;
      float4 x = *(const float4*)(src + (size_t)(m0 + row) * 1024 + k0 + kq);
      As[kq + 0][row] = x.x;
      As[kq + 1][row] = x.y;
      As[kq + 2][row] = x.z;
      As[kq + 3][row] = x.w;
    }
    int f = tid;
#pragma unroll
    for (int it = 0; it < 2; ++it, f += 256) {
      int kk = f >> 5, nq = (f & 31) << 2;
      *(float4*)&Bs[kk][nq] =
          *(const float4*)(w + (size_t)(k0 + kk) * 128 + nq);
    }
    __syncthreads();
#pragma unroll
    for (int kk = 0; kk < 16; ++kk) {
      float a[4], b[8];
      *(float4*)&a[0] = *(const float4*)&As[kk][ty << 2];
      *(float4*)&b[0] = *(const float4*)&Bs[kk][tx << 3];
      *(float4*)&b[4] = *(const float4*)&Bs[kk][(tx << 3) + 4];
#pragma unroll
      for (int i = 0; i < 4; ++i)
#pragma unroll
        for (int j = 0; j < 8; ++j) acc[i][j] = fmaf(a[i], b[j], acc[i][j]);
    }
    __syncthreads();
  }
#pragma unroll
  for (int i = 0; i < 4; ++i) {
    int r = m0 + (ty << 2) + i;
    float* drow = dst + (size_t)r * 128 + (tx << 3);
#pragma unroll
    for (int j = 0; j < 8; ++j) {
      float x = acc[i][j] + bv[(tx << 3) + j];
      drow[j] = silu_f(x);
    }
  }
}

// ---------------- K5: lin_kv[b] += clk^T @ cv / 4096 (split-K atomics) -----
__global__ __launch_bounds__(256) void k_linkv(
    const float* __restrict__ kp, const float* __restrict__ vv,
    const float* __restrict__ ks_g, const float* __restrict__ ks_b,
    float* __restrict__ linkv) {
  __shared__ float Ks[16][132];
  __shared__ float Vs[16][132];
  const int tid = threadIdx.x;
  const int tx = tid & 15, ty = tid >> 4;
  const int e0 = blockIdx.x << 7;
  const int nbase = blockIdx.z * 4096 + blockIdx.y * 256;
  float acc[8][8] = {};
  for (int n0 = 0; n0 < 256; n0 += 16) {
    int f = tid;
#pragma unroll
    for (int it = 0; it < 2; ++it, f += 256) {
      int nn = f >> 5, dq = (f & 31) << 2;
      float4 x = *(const float4*)(kp + (size_t)(nbase + n0 + nn) * 128 + dq);
      Ks[nn][dq + 0] = x.x * ks_g[128 + dq + 0] + ks_b[128 + dq + 0];
      Ks[nn][dq + 1] = x.y * ks_g[128 + dq + 1] + ks_b[128 + dq + 1];
      Ks[nn][dq + 2] = x.z * ks_g[128 + dq + 2] + ks_b[128 + dq + 2];
      Ks[nn][dq + 3] = x.w * ks_g[128 + dq + 3] + ks_b[128 + dq + 3];
    }
    f = tid;
#pragma unroll
    for (int it = 0; it < 2; ++it, f += 256) {
      int nn = f >> 5, eq = (f & 31) << 2;
      *(float4*)&Vs[nn][eq] =
          *(const float4*)(vv + (size_t)(nbase + n0 + nn) * 2048 + e0 + eq);
    }
    __syncthreads();
#pragma unroll
    for (int kk = 0; kk < 16; ++kk) {
      float a[8], b[8];
      *(float4*)&a[0] = *(const float4*)&Ks[kk][ty << 3];
      *(float4*)&a[4] = *(const float4*)&Ks[kk][(ty << 3) + 4];
      *(float4*)&b[0] = *(const float4*)&Vs[kk][tx << 3];
      *(float4*)&b[4] = *(const float4*)&Vs[kk][(tx << 3) + 4];
#pragma unroll
      for (int i = 0; i < 8; ++i)
#pragma unroll
        for (int j = 0; j < 8; ++j) acc[i][j] = fmaf(a[i], b[j], acc[i][j]);
    }
    __syncthreads();
  }
  const int b = blockIdx.z;
#pragma unroll
  for (int i = 0; i < 8; ++i) {
    int d = (ty << 3) + i;
    float* drow = linkv + ((size_t)b * 128 + d) * 2048 + e0 + (tx << 3);
#pragma unroll
    for (int j = 0; j < 8; ++j) atomicAdd(&drow[j], acc[i][j] * (1.f / 4096.f));
  }
}

// ---------------- K6a: attn = relu(cq@ck^T/G + bias)^2 -> quad_attn --------
__global__ __launch_bounds__(256) void k_attn(
    const float* __restrict__ qp, const float* __restrict__ kp,
    const float* __restrict__ qs_g, const float* __restrict__ qs_b,
    const float* __restrict__ ks_g, const float* __restrict__ ks_b,
    const float* __restrict__ bias, float* __restrict__ qa) {
  __shared__ float Qs[16][132];
  __shared__ float Ksl[16][132];
  const int tid = threadIdx.x;
  const int tx = tid & 15, ty = tid >> 4;
  const int i0 = blockIdx.x << 7, j0 = blockIdx.y << 7;
  const int gbase = blockIdx.z << 8;  // (b*16+g)*256 row base
  float acc[8][8] = {};
  for (int d0 = 0; d0 < 128; d0 += 16) {
    int f = tid;
#pragma unroll
    for (int it = 0; it < 2; ++it, f += 256) {
      int row = f >> 2, dq = (f & 3) << 2;
      float4 x = *(const float4*)(qp + (size_t)(gbase + i0 + row) * 128 + d0 + dq);
      Qs[dq + 0][row] = x.x * qs_g[d0 + dq + 0] + qs_b[d0 + dq + 0];
      Qs[dq + 1][row] = x.y * qs_g[d0 + dq + 1] + qs_b[d0 + dq + 1];
      Qs[dq + 2][row] = x.z * qs_g[d0 + dq + 2] + qs_b[d0 + dq + 2];
      Qs[dq + 3][row] = x.w * qs_g[d0 + dq + 3] + qs_b[d0 + dq + 3];
      float4 y = *(const float4*)(kp + (size_t)(gbase + j0 + row) * 128 + d0 + dq);
      Ksl[dq + 0][row] = y.x * ks_g[d0 + dq + 0] + ks_b[d0 + dq + 0];
      Ksl[dq + 1][row] = y.y * ks_g[d0 + dq + 1] + ks_b[d0 + dq + 1];
      Ksl[dq + 2][row] = y.z * ks_g[d0 + dq + 2] + ks_b[d0 + dq + 2];
      Ksl[dq + 3][row] = y.w * ks_g[d0 + dq + 3] + ks_b[d0 + dq + 3];
    }
    __syncthreads();
#pragma unroll
    for (int kk = 0; kk < 16; ++kk) {
      float a[8], b[8];
      *(float4*)&a[0] = *(const float4*)&Qs[kk][ty << 3];
      *(float4*)&a[4] = *(const float4*)&Qs[kk][(ty << 3) + 4];
      *(float4*)&b[0] = *(const float4*)&Ksl[kk][tx << 3];
      *(float4*)&b[4] = *(const float4*)&Ksl[kk][(tx << 3) + 4];
#pragma unroll
      for (int i = 0; i < 8; ++i)
#pragma unroll
        for (int j = 0; j < 8; ++j) acc[i][j] = fmaf(a[i], b[j], acc[i][j]);
    }
    __syncthreads();
  }
#pragma unroll
  for (int i = 0; i < 8; ++i) {
    int gi = i0 + (ty << 3) + i;
    float* drow = qa + (size_t)(gbase + gi) * 256 + j0 + (tx << 3);
    const float* brow = bias + (size_t)gi * 256 + j0 + (tx << 3);
#pragma unroll
    for (int j = 0; j < 8; ++j) {
      float s = acc[i][j] * (1.f / 256.f) + brow[j];
      float r = fmaxf(s, 0.f);
      drow[j] = r * r;
    }
  }
}

// ---------------- K6b: gate *= (attn@cv + clq@lin_kv)  [in-place] ----------
__global__ __launch_bounds__(256) void k_combine(
    const float* __restrict__ qa, const float* __restrict__ vv,
    const float* __restrict__ qp, const float* __restrict__ qs_g,
    const float* __restrict__ qs_b, const float* __restrict__ linkv,
    float* __restrict__ gate) {
  __shared__ float As[16][132];
  __shared__ float Bs[16][132];
  const int tid = threadIdx.x;
  const int tx = tid & 15, ty = tid >> 4;
  const int e0 = blockIdx.x << 7;
  const int i0 = blockIdx.y << 7;
  const int gbase = blockIdx.z << 8;
  const int bb = blockIdx.z >> 4;
  float acc[8][8] = {};
  // phase 1: attn @ cv, j over 256
  for (int j0 = 0; j0 < 256; j0 += 16) {
    int f = tid;
#pragma unroll
    for (int it = 0; it < 2; ++it, f += 256) {
      int row = f >> 2, jq = (f & 3) << 2;
      float4 x = *(const float4*)(qa + (size_t)(gbase + i0 + row) * 256 + j0 + jq);
      As[jq + 0][row] = x.x;
      As[jq + 1][row] = x.y;
      As[jq + 2][row] = x.z;
      As[jq + 3][row] = x.w;
    }
    f = tid;
#pragma unroll
    for (int it = 0; it < 2; ++it, f += 256) {
      int jj = f >> 5, eq = (f & 31) << 2;
      *(float4*)&Bs[jj][eq] =
          *(const float4*)(vv + (size_t)(gbase + j0 + jj) * 2048 + e0 + eq);
    }
    __syncthreads();
#pragma unroll
    for (int kk = 0; kk < 16; ++kk) {
      float a[8], b[8];
      *(float4*)&a[0] = *(const float4*)&As[kk][ty << 3];
      *(float4*)&a[4] = *(const float4*)&As[kk][(ty << 3) + 4];
      *(float4*)&b[0] = *(const float4*)&Bs[kk][tx << 3];
      *(float4*)&b[4] = *(const float4*)&Bs[kk][(tx << 3) + 4];
#pragma unroll
      for (int i = 0; i < 8; ++i)
#pragma unroll
        for (int j = 0; j < 8; ++j) acc[i][j] = fmaf(a[i], b[j], acc[i][j]);
    }
    __syncthreads();
  }
  // phase 2: clq @ lin_kv[b], d over 128
  for (int d0 = 0; d0 < 128; d0 += 16) {
    int f = tid;
#pragma unroll
    for (int it = 0; it < 2; ++it, f += 256) {
      int row = f >> 2, dq = (f & 3) << 2;
      float4 x = *(const float4*)(qp + (size_t)(gbase + i0 + row) * 128 + d0 + dq);
      As[dq + 0][row] = x.x * qs_g[128 + d0 + dq + 0] + qs_b[128 + d0 + dq + 0];
      As[dq + 1][row] = x.y * qs_g[128 + d0 + dq + 1] + qs_b[128 + d0 + dq + 1];
      As[dq + 2][row] = x.z * qs_g[128 + d0 + dq + 2] + qs_b[128 + d0 + dq + 2];
      As[dq + 3][row] = x.w * qs_g[128 + d0 + dq + 3] + qs_b[128 + d0 + dq + 3];
    }
    f = tid;
#pragma unroll
    for (int it = 0; it < 2; ++it, f += 256) {
      int dd = f >> 5, eq = (f & 31) << 2;
      *(float4*)&Bs[dd][eq] = *(const float4*)(
          linkv + ((size_t)bb * 128 + d0 + dd) * 2048 + e0 + eq);
    }
    __syncthreads();
#pragma unroll
    for (int kk = 0; kk < 16; ++kk) {
      float a[8], b[8];
      *(float4*)&a[0] = *(const float4*)&As[kk][ty << 3];
      *(float4*)&a[4] = *(const float4*)&As[kk][(ty << 3) + 4];
      *(float4*)&b[0] = *(const float4*)&Bs[kk][tx << 3];
      *(float4*)&b[4] = *(const float4*)&Bs[kk][(tx << 3) + 4];
#pragma unroll
      for (int i = 0; i < 8; ++i)
#pragma unroll
        for (int j = 0; j < 8; ++j) acc[i][j] = fmaf(a[i], b[j], acc[i][j]);
    }
    __syncthreads();
  }
#pragma unroll
  for (int i = 0; i < 8; ++i) {
    int r = gbase + i0 + (ty << 3) + i;
    float* grow = gate + (size_t)r * 2048 + e0 + (tx << 3);
#pragma unroll
    for (int j = 0; j < 8; ++j) grow[j] = grow[j] * acc[i][j];
  }
}

// ---------------- K7: out = accb @ w_out + b_out ---------------------------
__global__ __launch_bounds__(256) void k_gemm_out(
    const float* __restrict__ accb, const float* __restrict__ w_out,
    const float* __restrict__ b_out, float* __restrict__ out) {
  __shared__ float As[16][132];
  __shared__ float Bs[16][132];
  const int tid = threadIdx.x;
  const int tx = tid & 15, ty = tid >> 4;
  const int m0 = blockIdx.y << 7, n0 = blockIdx.x << 7;
  float acc[8][8] = {};
  for (int k0 = 0; k0 < 2048; k0 += 16) {
    int f = tid;
#pragma unroll
    for (int it = 0; it < 2; ++it, f += 256) {
      int row = f >> 2, kq = (f & 3) << 2;
      float4 x = *(const float4*)(accb + (size_t)(m0 + row) * 2048 + k0 + kq);
      As[kq + 0][row] = x.x;
      As[kq + 1][row] = x.y;
      As[kq + 2][row] = x.z;
      As[kq + 3][row] = x.w;
    }
    f = tid;
#pragma unroll
    for (int it = 0; it < 2; ++it, f += 256) {
      int kk = f >> 5, nq = (f & 31) << 2;
      *(float4*)&Bs[kk][nq] =
          *(const float4*)(w_out + (size_t)(k0 + kk) * 1024 + n0 + nq);
    }
    __syncthreads();
#pragma unroll
    for (int kk = 0; kk < 16; ++kk) {
      float a[8], b[8];
      *(float4*)&a[0] = *(const float4*)&As[kk][ty << 3];
      *(float4*)&a[4] = *(const float4*)&As[kk][(ty << 3) + 4];
      *(float4*)&b[0] = *(const float4*)&Bs[kk][tx << 3];
      *(float4*)&b[4] = *(const float4*)&Bs[kk][(tx << 3) + 4];
#pragma unroll
      for (int i = 0; i < 8; ++i)
#pragma unroll
        for (int j = 0; j < 8; ++j) acc[i][j] = fmaf(a[i], b[j], acc[i][j]);
    }
    __syncthreads();
  }
#pragma unroll
  for (int i = 0; i < 8; ++i) {
    int r = m0 + (ty << 3) + i;
    float* drow = out + (size_t)r * 1024 + n0 + (tx << 3);
#pragma unroll
    for (int j = 0; j < 8; ++j)
      drow[j] = acc[i][j] + b_out[n0 + (tx << 3) + j];
  }
}

// ---------------------------------------------------------------------------
extern "C" void kernel_launch(void* const* d_in, const int* in_sizes, int n_in,
                              void* d_out, int out_size, void* d_ws,
                              size_t ws_size, hipStream_t stream) {
  const float* q = (const float*)d_in[0];
  const float* k = (const float*)d_in[1];
  const float* v = (const float*)d_in[2];
  const float* ln_g = (const float*)d_in[3];
  const float* ln_b = (const float*)d_in[4];
  const float* w_hid = (const float*)d_in[5];
  const float* b_hid = (const float*)d_in[6];
  const float* w_q = (const float*)d_in[7];
  const float* b_q = (const float*)d_in[8];
  const float* w_k = (const float*)d_in[9];
  const float* b_k = (const float*)d_in[10];
  const float* qs_g = (const float*)d_in[11];
  const float* qs_b = (const float*)d_in[12];
  const float* ks_g = (const float*)d_in[13];
  const float* ks_b = (const float*)d_in[14];
  const float* rel = (const float*)d_in[15];
  const float* w_out = (const float*)d_in[16];
  const float* b_out = (const float*)d_in[17];

  // ws: only the two big [16384,2048] fp32 buffers (256 MiB total).
  if (ws_size < (size_t)268435456) return;  // diagnostic: clean absmax fail
  float* vv = (float*)d_ws;
  float* gate = vv + (size_t)16384 * 2048;  // also the combine output (accb)

  // d_out: out [16384,1024] then quad_attn [16384,256].
  float* out = (float*)d_out;
  float* qa = out + (size_t)16384 * 1024;
  // Small scratch inside the out region (fully overwritten by k_gemm_out):
  float* qp = out;                       // 2,097,152 floats
  float* kp = qp + (size_t)2097152;      // 2,097,152
  float* mean = kp + (size_t)2097152;    // 16384
  float* rstd = mean + 16384;            // 16384
  float* bias = rstd + 16384;            // 65536
  float* linkv = bias + 65536;           // 1,048,576  (ends < 5.4M of 16.8M)

  k_ln_stats<<<4096, 256, 0, stream>>>(v, mean, rstd);
  k_bias<<<256, 256, 0, stream>>>(rel, bias);
  k_zero<<<1024, 256, 0, stream>>>((float4*)linkv);
  k_gemm_hid<<<dim3(32, 128), 256, 0, stream>>>(v, mean, rstd, ln_g, ln_b,
                                                w_hid, b_hid, vv, gate);
  k_proj<<<dim3(256, 2), 256, 0, stream>>>(q, k, w_q, b_q, w_k, b_k, qp, kp);
  k_linkv<<<dim3(16, 16, 4), 256, 0, stream>>>(kp, vv, ks_g, ks_b, linkv);
  k_attn<<<dim3(2, 2, 64), 256, 0, stream>>>(qp, kp, qs_g, qs_b, ks_g, ks_b,
                                             bias, qa);
  k_combine<<<dim3(16, 2, 64), 256, 0, stream>>>(qa, vv, qp, qs_g, qs_b, linkv,
                                                 gate);
  k_gemm_out<<<dim3(8, 128), 256, 0, stream>>>(gate, w_out, b_out, out);
}

// Round 8
// 1549.513 us; speedup vs baseline: 2.2986x; 2.2986x over previous
//
#include <hip/hip_runtime.h>
#include <math.h>

// ---------------------------------------------------------------------------
// MixedChunkAttention — round 8 = round 6 resubmit (broker timeouts; the
// w_outT race fix has never executed).
// B=4 N=4096 D=1024 H=2048 2H=4096 QD=128 G=256 -> M=16384 rows.
// hid GEMM (137.4 GF) + out GEMM (68.7 GF): mfma_f32_16x16x32_bf16,
// 128x128 tile, 4 waves, BK=32, reg-staged LDS (pad to 40 shorts/row).
// ws: vv fp32 (134.2MB) | gate_bf (67.1MB, reused as w_outT after combine) |
//     accb_bf (67.1MB) = 256 MiB.
// ---------------------------------------------------------------------------

typedef __attribute__((ext_vector_type(8))) short short8v;
typedef __attribute__((ext_vector_type(4))) float f32x4;

static __device__ __forceinline__ float silu_f(float x) {
  return x / (1.f + expf(-x));
}
static __device__ __forceinline__ unsigned short f2bf(float x) {
  unsigned int u = __float_as_uint(x);
  unsigned int r = (u + 0x7FFFu + ((u >> 16) & 1u)) >> 16;  // RNE
  return (unsigned short)r;
}
static __device__ __forceinline__ float bf2f(unsigned short u) {
  return __uint_as_float(((unsigned int)u) << 16);
}

// ---------------- K0: zero linkv (atomics target) --------------------------
__global__ __launch_bounds__(256) void k_zero(float4* __restrict__ p) {
  p[(size_t)blockIdx.x * 256 + threadIdx.x] = make_float4(0.f, 0.f, 0.f, 0.f);
}

// ---------------- K1: layernorm row stats (mean, rstd) ---------------------
__global__ __launch_bounds__(256) void k_ln_stats(
    const float* __restrict__ v, float* __restrict__ mean,
    float* __restrict__ rstd) {
  int wid = threadIdx.x >> 6, lane = threadIdx.x & 63;
  int row = (blockIdx.x << 2) + wid;
  const float4* p = (const float4*)(v + (size_t)row * 1024);
  float s = 0.f, sq = 0.f;
#pragma unroll
  for (int i = 0; i < 4; ++i) {
    float4 x = p[lane + (i << 6)];
    s += (x.x + x.y) + (x.z + x.w);
    sq += x.x * x.x + x.y * x.y + x.z * x.z + x.w * x.w;
  }
#pragma unroll
  for (int m = 32; m; m >>= 1) {
    s += __shfl_xor(s, m);
    sq += __shfl_xor(sq, m);
  }
  if (lane == 0) {
    float mu = s * (1.f / 1024.f);
    float var = sq * (1.f / 1024.f) - mu * mu;
    mean[row] = mu;
    rstd[row] = rsqrtf(var + 1e-5f);
  }
}

// ---------------- K2: T5 relative position bias table ----------------------
__global__ __launch_bounds__(256) void k_bias(const float* __restrict__ rel,
                                              float* __restrict__ bias) {
  int i = blockIdx.x, j = threadIdx.x;
  int n = i - j;
  int ret = (n < 0) ? 16 : 0;
  int an = n < 0 ? -n : n;
  int bucket;
  if (an < 8)
    bucket = ret + an;
  else {
    int vl = 33 - __clz(an * an);
    bucket = ret + (vl < 15 ? vl : 15);
  }
  bias[(i << 8) + j] = rel[bucket] * 11.313708498984761f;  // *sqrt(128)
}

// ---------------- K2b: lnv_bf16 = bf16(LN(v)) ------------------------------
__global__ __launch_bounds__(256) void k_cvt_lnv(
    const float* __restrict__ v, const float* __restrict__ mean,
    const float* __restrict__ rstd, const float* __restrict__ ln_g,
    const float* __restrict__ ln_b, unsigned short* __restrict__ lnv) {
  size_t i = (size_t)blockIdx.x * 256 + threadIdx.x;  // 8-elem chunk
  int row = (int)(i >> 7), c = ((int)i & 127) << 3;
  float mu = mean[row], rs = rstd[row];
  const float* src = v + (size_t)row * 1024 + c;
  float4 x0 = *(const float4*)src;
  float4 x1 = *(const float4*)(src + 4);
  float4 g0 = *(const float4*)&ln_g[c];
  float4 g1 = *(const float4*)&ln_g[c + 4];
  float4 b0 = *(const float4*)&ln_b[c];
  float4 b1 = *(const float4*)&ln_b[c + 4];
  short8v ov;
  ov[0] = (short)f2bf((x0.x - mu) * rs * g0.x + b0.x);
  ov[1] = (short)f2bf((x0.y - mu) * rs * g0.y + b0.y);
  ov[2] = (short)f2bf((x0.z - mu) * rs * g0.z + b0.z);
  ov[3] = (short)f2bf((x0.w - mu) * rs * g0.w + b0.w);
  ov[4] = (short)f2bf((x1.x - mu) * rs * g1.x + b1.x);
  ov[5] = (short)f2bf((x1.y - mu) * rs * g1.y + b1.y);
  ov[6] = (short)f2bf((x1.z - mu) * rs * g1.z + b1.z);
  ov[7] = (short)f2bf((x1.w - mu) * rs * g1.w + b1.w);
  *(short8v*)&lnv[(size_t)row * 1024 + c] = ov;
}

// ---------------- K2c: dst[C][R] bf16 = transpose(src[R][C] fp32) ----------
__global__ __launch_bounds__(256) void k_transpose_cvt(
    const float* __restrict__ src, unsigned short* __restrict__ dst, int R,
    int C) {
  __shared__ float T[32][33];
  int tx = threadIdx.x & 31, ty = threadIdx.x >> 5;  // ty 0..7
  int r0 = blockIdx.y << 5, c0 = blockIdx.x << 5;
#pragma unroll
  for (int jj = 0; jj < 4; ++jj)
    T[ty * 4 + jj][tx] = src[(size_t)(r0 + ty * 4 + jj) * C + c0 + tx];
  __syncthreads();
#pragma unroll
  for (int jj = 0; jj < 4; ++jj)
    dst[(size_t)(c0 + ty * 4 + jj) * R + r0 + tx] = f2bf(T[tx][ty * 4 + jj]);
}

// ---------------- K3: MFMA hid GEMM: silu(lnv @ w_hidT^T + b_hid) ----------
// A [16384][1024] bf16, BT [4096][1024] bf16. vv fp32 (n<2048), gate bf16.
__global__ __launch_bounds__(256) void k_gemm_hid_mfma(
    const unsigned short* __restrict__ A, const unsigned short* __restrict__ BT,
    const float* __restrict__ b_hid, float* __restrict__ vv,
    unsigned short* __restrict__ gate) {
  __shared__ unsigned short Abuf[128 * 40];
  __shared__ unsigned short Bbuf[128 * 40];
  const int tid = threadIdx.x;
  const int lane = tid & 63, wave = tid >> 6;
  const int wm = wave >> 1, wn = wave & 1;
  const int m0 = blockIdx.y << 7, n0 = blockIdx.x << 7;
  const int K = 1024;
  f32x4 acc[4][4] = {};
  const int arow = tid >> 2, akq = (tid & 3) << 3;
  const int lr = lane & 15, lk = (lane >> 4) << 3;
  for (int k0 = 0; k0 < K; k0 += 32) {
    short8v va0 = *(const short8v*)&A[(size_t)(m0 + arow) * K + k0 + akq];
    short8v va1 = *(const short8v*)&A[(size_t)(m0 + arow + 64) * K + k0 + akq];
    short8v vb0 = *(const short8v*)&BT[(size_t)(n0 + arow) * K + k0 + akq];
    short8v vb1 = *(const short8v*)&BT[(size_t)(n0 + arow + 64) * K + k0 + akq];
    __syncthreads();
    *(short8v*)&Abuf[arow * 40 + akq] = va0;
    *(short8v*)&Abuf[(arow + 64) * 40 + akq] = va1;
    *(short8v*)&Bbuf[arow * 40 + akq] = vb0;
    *(short8v*)&Bbuf[(arow + 64) * 40 + akq] = vb1;
    __syncthreads();
    short8v af[4], bf[4];
#pragma unroll
    for (int i = 0; i < 4; ++i) {
      af[i] = *(const short8v*)&Abuf[(wm * 64 + i * 16 + lr) * 40 + lk];
      bf[i] = *(const short8v*)&Bbuf[(wn * 64 + i * 16 + lr) * 40 + lk];
    }
#pragma unroll
    for (int i = 0; i < 4; ++i)
#pragma unroll
      for (int j = 0; j < 4; ++j)
        acc[i][j] = __builtin_amdgcn_mfma_f32_16x16x32_bf16(af[i], bf[j],
                                                            acc[i][j], 0, 0, 0);
  }
  const int er = (lane >> 4) << 2, ec = lane & 15;
  const bool isv = n0 < 2048;
#pragma unroll
  for (int i = 0; i < 4; ++i) {
#pragma unroll
    for (int j = 0; j < 4; ++j) {
      int col = n0 + wn * 64 + j * 16 + ec;
      float bb = b_hid[col];
#pragma unroll
      for (int r = 0; r < 4; ++r) {
        int row = m0 + wm * 64 + i * 16 + er + r;
        float xv = silu_f(acc[i][j][r] + bb);
        if (isv)
          vv[(size_t)row * 2048 + col] = xv;
        else
          gate[(size_t)row * 2048 + (col - 2048)] = f2bf(xv);
      }
    }
  }
}

// ---------------- K7: MFMA out GEMM: accb_bf @ w_outT^T + b_out ------------
__global__ __launch_bounds__(256) void k_gemm_out_mfma(
    const unsigned short* __restrict__ A, const unsigned short* __restrict__ BT,
    const float* __restrict__ b_out, float* __restrict__ out) {
  __shared__ unsigned short Abuf[128 * 40];
  __shared__ unsigned short Bbuf[128 * 40];
  const int tid = threadIdx.x;
  const int lane = tid & 63, wave = tid >> 6;
  const int wm = wave >> 1, wn = wave & 1;
  const int m0 = blockIdx.y << 7, n0 = blockIdx.x << 7;
  const int K = 2048;
  f32x4 acc[4][4] = {};
  const int arow = tid >> 2, akq = (tid & 3) << 3;
  const int lr = lane & 15, lk = (lane >> 4) << 3;
  for (int k0 = 0; k0 < K; k0 += 32) {
    short8v va0 = *(const short8v*)&A[(size_t)(m0 + arow) * K + k0 + akq];
    short8v va1 = *(const short8v*)&A[(size_t)(m0 + arow + 64) * K + k0 + akq];
    short8v vb0 = *(const short8v*)&BT[(size_t)(n0 + arow) * K + k0 + akq];
    short8v vb1 = *(const short8v*)&BT[(size_t)(n0 + arow + 64) * K + k0 + akq];
    __syncthreads();
    *(short8v*)&Abuf[arow * 40 + akq] = va0;
    *(short8v*)&Abuf[(arow + 64) * 40 + akq] = va1;
    *(short8v*)&Bbuf[arow * 40 + akq] = vb0;
    *(short8v*)&Bbuf[(arow + 64) * 40 + akq] = vb1;
    __syncthreads();
    short8v af[4], bf[4];
#pragma unroll
    for (int i = 0; i < 4; ++i) {
      af[i] = *(const short8v*)&Abuf[(wm * 64 + i * 16 + lr) * 40 + lk];
      bf[i] = *(const short8v*)&Bbuf[(wn * 64 + i * 16 + lr) * 40 + lk];
    }
#pragma unroll
    for (int i = 0; i < 4; ++i)
#pragma unroll
      for (int j = 0; j < 4; ++j)
        acc[i][j] = __builtin_amdgcn_mfma_f32_16x16x32_bf16(af[i], bf[j],
                                                            acc[i][j], 0, 0, 0);
  }
  const int er = (lane >> 4) << 2, ec = lane & 15;
#pragma unroll
  for (int i = 0; i < 4; ++i) {
#pragma unroll
    for (int j = 0; j < 4; ++j) {
      int col = n0 + wn * 64 + j * 16 + ec;
      float bb = b_out[col];
#pragma unroll
      for (int r = 0; r < 4; ++r) {
        int row = m0 + wm * 64 + i * 16 + er + r;
        out[(size_t)row * 1024 + col] = acc[i][j][r] + bb;
      }
    }
  }
}

// ---------------- K4: qp = silu(q@w_q+b_q), kp = silu(k@w_k+b_k) -----------
__global__ __launch_bounds__(256) void k_proj(
    const float* __restrict__ q, const float* __restrict__ k,
    const float* __restrict__ w_q, const float* __restrict__ b_q,
    const float* __restrict__ w_k, const float* __restrict__ b_k,
    float* __restrict__ qp, float* __restrict__ kp) {
  __shared__ float As[16][68];
  __shared__ float Bs[16][132];
  const int tid = threadIdx.x;
  const int tx = tid & 15, ty = tid >> 4;
  const int m0 = blockIdx.x << 6;
  const bool isq = blockIdx.y == 0;
  const float* src = isq ? q : k;
  const float* w = isq ? w_q : w_k;
  const float* bv = isq ? b_q : b_k;
  float* dst = isq ? qp : kp;
  float acc[4][8] = {};
  for (int k0 = 0; k0 < 1024; k0 += 16) {
    {
      int row = tid >> 2, kq = (tid & 3) << 2;
      float4 x = *(const float4*)(src + (size_t)(m0 + row) * 1024 + k0 + kq);
      As[kq + 0][row] = x.x;
      As[kq + 1][row] = x.y;
      As[kq + 2][row] = x.z;
      As[kq + 3][row] = x.w;
    }
    int f = tid;
#pragma unroll
    for (int it = 0; it < 2; ++it, f += 256) {
      int kk = f >> 5, nq = (f & 31) << 2;
      *(float4*)&Bs[kk][nq] = *(const float4*)(w + (size_t)(k0 + kk) * 128 + nq);
    }
    __syncthreads();
#pragma unroll
    for (int kk = 0; kk < 16; ++kk) {
      float a[4], b[8];
      *(float4*)&a[0] = *(const float4*)&As[kk][ty << 2];
      *(float4*)&b[0] = *(const float4*)&Bs[kk][tx << 3];
      *(float4*)&b[4] = *(const float4*)&Bs[kk][(tx << 3) + 4];
#pragma unroll
      for (int i = 0; i < 4; ++i)
#pragma unroll
        for (int j = 0; j < 8; ++j) acc[i][j] = fmaf(a[i], b[j], acc[i][j]);
    }
    __syncthreads();
  }
#pragma unroll
  for (int i = 0; i < 4; ++i) {
    int r = m0 + (ty << 2) + i;
    float* drow = dst + (size_t)r * 128 + (tx << 3);
#pragma unroll
    for (int j = 0; j < 8; ++j) {
      float x = acc[i][j] + bv[(tx << 3) + j];
      drow[j] = silu_f(x);
    }
  }
}

// ---------------- K5: lin_kv[b] += clk^T @ cv / 4096 (split-K atomics) -----
__global__ __launch_bounds__(256) void k_linkv(
    const float* __restrict__ kp, const float* __restrict__ vv,
    const float* __restrict__ ks_g, const float* __restrict__ ks_b,
    float* __restrict__ linkv) {
  __shared__ float Ks[16][132];
  __shared__ float Vs[16][132];
  const int tid = threadIdx.x;
  const int tx = tid & 15, ty = tid >> 4;
  const int e0 = blockIdx.x << 7;
  const int nbase = blockIdx.z * 4096 + blockIdx.y * 256;
  float acc[8][8] = {};
  for (int n0 = 0; n0 < 256; n0 += 16) {
    int f = tid;
#pragma unroll
    for (int it = 0; it < 2; ++it, f += 256) {
      int nn = f >> 5, dq = (f & 31) << 2;
      float4 x = *(const float4*)(kp + (size_t)(nbase + n0 + nn) * 128 + dq);
      Ks[nn][dq + 0] = x.x * ks_g[128 + dq + 0] + ks_b[128 + dq + 0];
      Ks[nn][dq + 1] = x.y * ks_g[128 + dq + 1] + ks_b[128 + dq + 1];
      Ks[nn][dq + 2] = x.z * ks_g[128 + dq + 2] + ks_b[128 + dq + 2];
      Ks[nn][dq + 3] = x.w * ks_g[128 + dq + 3] + ks_b[128 + dq + 3];
    }
    f = tid;
#pragma unroll
    for (int it = 0; it < 2; ++it, f += 256) {
      int nn = f >> 5, eq = (f & 31) << 2;
      *(float4*)&Vs[nn][eq] =
          *(const float4*)(vv + (size_t)(nbase + n0 + nn) * 2048 + e0 + eq);
    }
    __syncthreads();
#pragma unroll
    for (int kk = 0; kk < 16; ++kk) {
      float a[8], b[8];
      *(float4*)&a[0] = *(const float4*)&Ks[kk][ty << 3];
      *(float4*)&a[4] = *(const float4*)&Ks[kk][(ty << 3) + 4];
      *(float4*)&b[0] = *(const float4*)&Vs[kk][tx << 3];
      *(float4*)&b[4] = *(const float4*)&Vs[kk][(tx << 3) + 4];
#pragma unroll
      for (int i = 0; i < 8; ++i)
#pragma unroll
        for (int j = 0; j < 8; ++j) acc[i][j] = fmaf(a[i], b[j], acc[i][j]);
    }
    __syncthreads();
  }
  const int b = blockIdx.z;
#pragma unroll
  for (int i = 0; i < 8; ++i) {
    int d = (ty << 3) + i;
    float* drow = linkv + ((size_t)b * 128 + d) * 2048 + e0 + (tx << 3);
#pragma unroll
    for (int j = 0; j < 8; ++j) atomicAdd(&drow[j], acc[i][j] * (1.f / 4096.f));
  }
}

// ---------------- K6a: attn = relu(cq@ck^T/G + bias)^2 -> quad_attn --------
__global__ __launch_bounds__(256) void k_attn(
    const float* __restrict__ qp, const float* __restrict__ kp,
    const float* __restrict__ qs_g, const float* __restrict__ qs_b,
    const float* __restrict__ ks_g, const float* __restrict__ ks_b,
    const float* __restrict__ bias, float* __restrict__ qa) {
  __shared__ float Qs[16][132];
  __shared__ float Ksl[16][132];
  const int tid = threadIdx.x;
  const int tx = tid & 15, ty = tid >> 4;
  const int i0 = blockIdx.x << 7, j0 = blockIdx.y << 7;
  const int gbase = blockIdx.z << 8;
  float acc[8][8] = {};
  for (int d0 = 0; d0 < 128; d0 += 16) {
    int f = tid;
#pragma unroll
    for (int it = 0; it < 2; ++it, f += 256) {
      int row = f >> 2, dq = (f & 3) << 2;
      float4 x = *(const float4*)(qp + (size_t)(gbase + i0 + row) * 128 + d0 + dq);
      Qs[dq + 0][row] = x.x * qs_g[d0 + dq + 0] + qs_b[d0 + dq + 0];
      Qs[dq + 1][row] = x.y * qs_g[d0 + dq + 1] + qs_b[d0 + dq + 1];
      Qs[dq + 2][row] = x.z * qs_g[d0 + dq + 2] + qs_b[d0 + dq + 2];
      Qs[dq + 3][row] = x.w * qs_g[d0 + dq + 3] + qs_b[d0 + dq + 3];
      float4 y = *(const float4*)(kp + (size_t)(gbase + j0 + row) * 128 + d0 + dq);
      Ksl[dq + 0][row] = y.x * ks_g[d0 + dq + 0] + ks_b[d0 + dq + 0];
      Ksl[dq + 1][row] = y.y * ks_g[d0 + dq + 1] + ks_b[d0 + dq + 1];
      Ksl[dq + 2][row] = y.z * ks_g[d0 + dq + 2] + ks_b[d0 + dq + 2];
      Ksl[dq + 3][row] = y.w * ks_g[d0 + dq + 3] + ks_b[d0 + dq + 3];
    }
    __syncthreads();
#pragma unroll
    for (int kk = 0; kk < 16; ++kk) {
      float a[8], b[8];
      *(float4*)&a[0] = *(const float4*)&Qs[kk][ty << 3];
      *(float4*)&a[4] = *(const float4*)&Qs[kk][(ty << 3) + 4];
      *(float4*)&b[0] = *(const float4*)&Ksl[kk][tx << 3];
      *(float4*)&b[4] = *(const float4*)&Ksl[kk][(tx << 3) + 4];
#pragma unroll
      for (int i = 0; i < 8; ++i)
#pragma unroll
        for (int j = 0; j < 8; ++j) acc[i][j] = fmaf(a[i], b[j], acc[i][j]);
    }
    __syncthreads();
  }
#pragma unroll
  for (int i = 0; i < 8; ++i) {
    int gi = i0 + (ty << 3) + i;
    float* drow = qa + (size_t)(gbase + gi) * 256 + j0 + (tx << 3);
    const float* brow = bias + (size_t)gi * 256 + j0 + (tx << 3);
#pragma unroll
    for (int j = 0; j < 8; ++j) {
      float s = acc[i][j] * (1.f / 256.f) + brow[j];
      float r = fmaxf(s, 0.f);
      drow[j] = r * r;
    }
  }
}

// ---------------- K6b: accb_bf = bf16(gate_bf * (attn@cv + clq@lin_kv)) ----
__global__ __launch_bounds__(256) void k_combine(
    const float* __restrict__ qa, const float* __restrict__ vv,
    const float* __restrict__ qp, const float* __restrict__ qs_g,
    const float* __restrict__ qs_b, const float* __restrict__ linkv,
    const unsigned short* __restrict__ gate_bf,
    unsigned short* __restrict__ accb_bf) {
  __shared__ float As[16][132];
  __shared__ float Bs[16][132];
  const int tid = threadIdx.x;
  const int tx = tid & 15, ty = tid >> 4;
  const int e0 = blockIdx.x << 7;
  const int i0 = blockIdx.y << 7;
  const int gbase = blockIdx.z << 8;
  const int bb = blockIdx.z >> 4;
  float acc[8][8] = {};
  for (int j0 = 0; j0 < 256; j0 += 16) {
    int f = tid;
#pragma unroll
    for (int it = 0; it < 2; ++it, f += 256) {
      int row = f >> 2, jq = (f & 3) << 2;
      float4 x = *(const float4*)(qa + (size_t)(gbase + i0 + row) * 256 + j0 + jq);
      As[jq + 0][row] = x.x;
      As[jq + 1][row] = x.y;
      As[jq + 2][row] = x.z;
      As[jq + 3][row] = x.w;
    }
    f = tid;
#pragma unroll
    for (int it = 0; it < 2; ++it, f += 256) {
      int jj = f >> 5, eq = (f & 31) << 2;
      *(float4*)&Bs[jj][eq] =
          *(const float4*)(vv + (size_t)(gbase + j0 + jj) * 2048 + e0 + eq);
    }
    __syncthreads();
#pragma unroll
    for (int kk = 0; kk < 16; ++kk) {
      float a[8], b[8];
      *(float4*)&a[0] = *(const float4*)&As[kk][ty << 3];
      *(float4*)&a[4] = *(const float4*)&As[kk][(ty << 3) + 4];
      *(float4*)&b[0] = *(const float4*)&Bs[kk][tx << 3];
      *(float4*)&b[4] = *(const float4*)&Bs[kk][(tx << 3) + 4];
#pragma unroll
      for (int i = 0; i < 8; ++i)
#pragma unroll
        for (int j = 0; j < 8; ++j) acc[i][j] = fmaf(a[i], b[j], acc[i][j]);
    }
    __syncthreads();
  }
  for (int d0 = 0; d0 < 128; d0 += 16) {
    int f = tid;
#pragma unroll
    for (int it = 0; it < 2; ++it, f += 256) {
      int row = f >> 2, dq = (f & 3) << 2;
      float4 x = *(const float4*)(qp + (size_t)(gbase + i0 + row) * 128 + d0 + dq);
      As[dq + 0][row] = x.x * qs_g[128 + d0 + dq + 0] + qs_b[128 + d0 + dq + 0];
      As[dq + 1][row] = x.y * qs_g[128 + d0 + dq + 1] + qs_b[128 + d0 + dq + 1];
      As[dq + 2][row] = x.z * qs_g[128 + d0 + dq + 2] + qs_b[128 + d0 + dq + 2];
      As[dq + 3][row] = x.w * qs_g[128 + d0 + dq + 3] + qs_b[128 + d0 + dq + 3];
    }
    f = tid;
#pragma unroll
    for (int it = 0; it < 2; ++it, f += 256) {
      int dd = f >> 5, eq = (f & 31) << 2;
      *(float4*)&Bs[dd][eq] = *(const float4*)(
          linkv + ((size_t)bb * 128 + d0 + dd) * 2048 + e0 + eq);
    }
    __syncthreads();
#pragma unroll
    for (int kk = 0; kk < 16; ++kk) {
      float a[8], b[8];
      *(float4*)&a[0] = *(const float4*)&As[kk][ty << 3];
      *(float4*)&a[4] = *(const float4*)&As[kk][(ty << 3) + 4];
      *(float4*)&b[0] = *(const float4*)&Bs[kk][tx << 3];
      *(float4*)&b[4] = *(const float4*)&Bs[kk][(tx << 3) + 4];
#pragma unroll
      for (int i = 0; i < 8; ++i)
#pragma unroll
        for (int j = 0; j < 8; ++j) acc[i][j] = fmaf(a[i], b[j], acc[i][j]);
    }
    __syncthreads();
  }
#pragma unroll
  for (int i = 0; i < 8; ++i) {
    size_t r = (size_t)(gbase + i0 + (ty << 3) + i);
    const unsigned short* grow = gate_bf + r * 2048 + e0 + (tx << 3);
    unsigned short* arow = accb_bf + r * 2048 + e0 + (tx << 3);
#pragma unroll
    for (int j = 0; j < 8; ++j) arow[j] = f2bf(bf2f(grow[j]) * acc[i][j]);
  }
}

// ---------------------------------------------------------------------------
extern "C" void kernel_launch(void* const* d_in, const int* in_sizes, int n_in,
                              void* d_out, int out_size, void* d_ws,
                              size_t ws_size, hipStream_t stream) {
  const float* q = (const float*)d_in[0];
  const float* k = (const float*)d_in[1];
  const float* v = (const float*)d_in[2];
  const float* ln_g = (const float*)d_in[3];
  const float* ln_b = (const float*)d_in[4];
  const float* w_hid = (const float*)d_in[5];
  const float* b_hid = (const float*)d_in[6];
  const float* w_q = (const float*)d_in[7];
  const float* b_q = (const float*)d_in[8];
  const float* w_k = (const float*)d_in[9];
  const float* b_k = (const float*)d_in[10];
  const float* qs_g = (const float*)d_in[11];
  const float* qs_b = (const float*)d_in[12];
  const float* ks_g = (const float*)d_in[13];
  const float* ks_b = (const float*)d_in[14];
  const float* rel = (const float*)d_in[15];
  const float* w_out = (const float*)d_in[16];
  const float* b_out = (const float*)d_in[17];

  if (ws_size < (size_t)268435456) return;
  float* vv = (float*)d_ws;                                    // 134.2 MB
  unsigned short* gate_bf = (unsigned short*)(vv + (size_t)16384 * 2048);
  unsigned short* accb_bf = gate_bf + (size_t)16384 * 2048;    // ends 256 MiB
  // w_outT reuses the gate_bf region AFTER k_combine's last read of gate_bf.
  unsigned short* w_outT = gate_bf;  // 2048*1024 bf16 = 4 MiB, fits easily

  float* out = (float*)d_out;                  // 16,777,216 floats
  float* qa = out + (size_t)16384 * 1024;      // output 2
  // scratch inside out region (all dead before k_gemm_out_mfma writes out):
  float* qp = out;                             // 2,097,152 f
  float* kp = qp + 2097152;                    // 2,097,152 f
  float* mean = kp + 2097152;                  // 16384
  float* rstd = mean + 16384;                  // 16384
  float* bias = rstd + 16384;                  // 65536
  float* linkv = bias + 65536;                 // 1,048,576 -> ends 5,341,184
  unsigned short* lnv = (unsigned short*)(linkv + 1048576);  // 16,777,216 bf16
  unsigned short* w_hidT = (unsigned short*)(out + 13729792);  // 4,194,304 bf16

  k_ln_stats<<<4096, 256, 0, stream>>>(v, mean, rstd);
  k_bias<<<256, 256, 0, stream>>>(rel, bias);
  k_zero<<<1024, 256, 0, stream>>>((float4*)linkv);
  k_cvt_lnv<<<8192, 256, 0, stream>>>(v, mean, rstd, ln_g, ln_b, lnv);
  k_transpose_cvt<<<dim3(128, 32), 256, 0, stream>>>(w_hid, w_hidT, 1024, 4096);
  k_gemm_hid_mfma<<<dim3(32, 128), 256, 0, stream>>>(lnv, w_hidT, b_hid, vv,
                                                     gate_bf);
  k_proj<<<dim3(256, 2), 256, 0, stream>>>(q, k, w_q, b_q, w_k, b_k, qp, kp);
  k_linkv<<<dim3(16, 16, 4), 256, 0, stream>>>(kp, vv, ks_g, ks_b, linkv);
  k_attn<<<dim3(2, 2, 64), 256, 0, stream>>>(qp, kp, qs_g, qs_b, ks_g, ks_b,
                                             bias, qa);
  k_combine<<<dim3(16, 2, 64), 256, 0, stream>>>(qa, vv, qp, qs_g, qs_b, linkv,
                                                 gate_bf, accb_bf);
  // transpose w_out into the (now-dead) gate_bf region, then final GEMM.
  k_transpose_cvt<<<dim3(32, 64), 256, 0, stream>>>(w_out, w_outT, 2048, 1024);
  k_gemm_out_mfma<<<dim3(8, 128), 256, 0, stream>>>(accb_bf, w_outT, b_out,
                                                    out);
}

// Round 10
// 1100.273 us; speedup vs baseline: 3.2372x; 1.4083x over previous
//
#include <hip/hip_runtime.h>
#include <math.h>

// ---------------------------------------------------------------------------
// MixedChunkAttention — round 10 = round 9 resubmit (broker timeout; the
// atomic-free k_linkv has never executed).
// Round-8 baseline: 1549us, k_linkv 530us w/ 512MiB atomic WRITE_SIZE.
// This round: 8-way split-K fp32 partials (dead lnv region) + reduce kernel.
// B=4 N=4096 D=1024 H=2048 2H=4096 QD=128 G=256 -> M=16384 rows.
// hid GEMM + out GEMM: mfma_f32_16x16x32_bf16, 128x128 tile, reg-staged LDS.
// ws: vv fp32 (134.2MB) | gate_bf (67.1MB, reused as w_outT) | accb_bf
// (67.1MB) = 256 MiB.
// ---------------------------------------------------------------------------

typedef __attribute__((ext_vector_type(8))) short short8v;
typedef __attribute__((ext_vector_type(4))) float f32x4;

static __device__ __forceinline__ float silu_f(float x) {
  return x / (1.f + expf(-x));
}
static __device__ __forceinline__ unsigned short f2bf(float x) {
  unsigned int u = __float_as_uint(x);
  unsigned int r = (u + 0x7FFFu + ((u >> 16) & 1u)) >> 16;  // RNE
  return (unsigned short)r;
}
static __device__ __forceinline__ float bf2f(unsigned short u) {
  return __uint_as_float(((unsigned int)u) << 16);
}

// ---------------- K1: layernorm row stats (mean, rstd) ---------------------
__global__ __launch_bounds__(256) void k_ln_stats(
    const float* __restrict__ v, float* __restrict__ mean,
    float* __restrict__ rstd) {
  int wid = threadIdx.x >> 6, lane = threadIdx.x & 63;
  int row = (blockIdx.x << 2) + wid;
  const float4* p = (const float4*)(v + (size_t)row * 1024);
  float s = 0.f, sq = 0.f;
#pragma unroll
  for (int i = 0; i < 4; ++i) {
    float4 x = p[lane + (i << 6)];
    s += (x.x + x.y) + (x.z + x.w);
    sq += x.x * x.x + x.y * x.y + x.z * x.z + x.w * x.w;
  }
#pragma unroll
  for (int m = 32; m; m >>= 1) {
    s += __shfl_xor(s, m);
    sq += __shfl_xor(sq, m);
  }
  if (lane == 0) {
    float mu = s * (1.f / 1024.f);
    float var = sq * (1.f / 1024.f) - mu * mu;
    mean[row] = mu;
    rstd[row] = rsqrtf(var + 1e-5f);
  }
}

// ---------------- K2: T5 relative position bias table ----------------------
__global__ __launch_bounds__(256) void k_bias(const float* __restrict__ rel,
                                              float* __restrict__ bias) {
  int i = blockIdx.x, j = threadIdx.x;
  int n = i - j;
  int ret = (n < 0) ? 16 : 0;
  int an = n < 0 ? -n : n;
  int bucket;
  if (an < 8)
    bucket = ret + an;
  else {
    int vl = 33 - __clz(an * an);
    bucket = ret + (vl < 15 ? vl : 15);
  }
  bias[(i << 8) + j] = rel[bucket] * 11.313708498984761f;  // *sqrt(128)
}

// ---------------- K2b: lnv_bf16 = bf16(LN(v)) ------------------------------
__global__ __launch_bounds__(256) void k_cvt_lnv(
    const float* __restrict__ v, const float* __restrict__ mean,
    const float* __restrict__ rstd, const float* __restrict__ ln_g,
    const float* __restrict__ ln_b, unsigned short* __restrict__ lnv) {
  size_t i = (size_t)blockIdx.x * 256 + threadIdx.x;  // 8-elem chunk
  int row = (int)(i >> 7), c = ((int)i & 127) << 3;
  float mu = mean[row], rs = rstd[row];
  const float* src = v + (size_t)row * 1024 + c;
  float4 x0 = *(const float4*)src;
  float4 x1 = *(const float4*)(src + 4);
  float4 g0 = *(const float4*)&ln_g[c];
  float4 g1 = *(const float4*)&ln_g[c + 4];
  float4 b0 = *(const float4*)&ln_b[c];
  float4 b1 = *(const float4*)&ln_b[c + 4];
  short8v ov;
  ov[0] = (short)f2bf((x0.x - mu) * rs * g0.x + b0.x);
  ov[1] = (short)f2bf((x0.y - mu) * rs * g0.y + b0.y);
  ov[2] = (short)f2bf((x0.z - mu) * rs * g0.z + b0.z);
  ov[3] = (short)f2bf((x0.w - mu) * rs * g0.w + b0.w);
  ov[4] = (short)f2bf((x1.x - mu) * rs * g1.x + b1.x);
  ov[5] = (short)f2bf((x1.y - mu) * rs * g1.y + b1.y);
  ov[6] = (short)f2bf((x1.z - mu) * rs * g1.z + b1.z);
  ov[7] = (short)f2bf((x1.w - mu) * rs * g1.w + b1.w);
  *(short8v*)&lnv[(size_t)row * 1024 + c] = ov;
}

// ---------------- K2c: dst[C][R] bf16 = transpose(src[R][C] fp32) ----------
__global__ __launch_bounds__(256) void k_transpose_cvt(
    const float* __restrict__ src, unsigned short* __restrict__ dst, int R,
    int C) {
  __shared__ float T[32][33];
  int tx = threadIdx.x & 31, ty = threadIdx.x >> 5;  // ty 0..7
  int r0 = blockIdx.y << 5, c0 = blockIdx.x << 5;
#pragma unroll
  for (int jj = 0; jj < 4; ++jj)
    T[ty * 4 + jj][tx] = src[(size_t)(r0 + ty * 4 + jj) * C + c0 + tx];
  __syncthreads();
#pragma unroll
  for (int jj = 0; jj < 4; ++jj)
    dst[(size_t)(c0 + ty * 4 + jj) * R + r0 + tx] = f2bf(T[tx][ty * 4 + jj]);
}

// ---------------- K3: MFMA hid GEMM: silu(lnv @ w_hidT^T + b_hid) ----------
// A [16384][1024] bf16, BT [4096][1024] bf16. vv fp32 (n<2048), gate bf16.
__global__ __launch_bounds__(256) void k_gemm_hid_mfma(
    const unsigned short* __restrict__ A, const unsigned short* __restrict__ BT,
    const float* __restrict__ b_hid, float* __restrict__ vv,
    unsigned short* __restrict__ gate) {
  __shared__ unsigned short Abuf[128 * 40];
  __shared__ unsigned short Bbuf[128 * 40];
  const int tid = threadIdx.x;
  const int lane = tid & 63, wave = tid >> 6;
  const int wm = wave >> 1, wn = wave & 1;
  const int m0 = blockIdx.y << 7, n0 = blockIdx.x << 7;
  const int K = 1024;
  f32x4 acc[4][4] = {};
  const int arow = tid >> 2, akq = (tid & 3) << 3;
  const int lr = lane & 15, lk = (lane >> 4) << 3;
  for (int k0 = 0; k0 < K; k0 += 32) {
    short8v va0 = *(const short8v*)&A[(size_t)(m0 + arow) * K + k0 + akq];
    short8v va1 = *(const short8v*)&A[(size_t)(m0 + arow + 64) * K + k0 + akq];
    short8v vb0 = *(const short8v*)&BT[(size_t)(n0 + arow) * K + k0 + akq];
    short8v vb1 = *(const short8v*)&BT[(size_t)(n0 + arow + 64) * K + k0 + akq];
    __syncthreads();
    *(short8v*)&Abuf[arow * 40 + akq] = va0;
    *(short8v*)&Abuf[(arow + 64) * 40 + akq] = va1;
    *(short8v*)&Bbuf[arow * 40 + akq] = vb0;
    *(short8v*)&Bbuf[(arow + 64) * 40 + akq] = vb1;
    __syncthreads();
    short8v af[4], bf[4];
#pragma unroll
    for (int i = 0; i < 4; ++i) {
      af[i] = *(const short8v*)&Abuf[(wm * 64 + i * 16 + lr) * 40 + lk];
      bf[i] = *(const short8v*)&Bbuf[(wn * 64 + i * 16 + lr) * 40 + lk];
    }
#pragma unroll
    for (int i = 0; i < 4; ++i)
#pragma unroll
      for (int j = 0; j < 4; ++j)
        acc[i][j] = __builtin_amdgcn_mfma_f32_16x16x32_bf16(af[i], bf[j],
                                                            acc[i][j], 0, 0, 0);
  }
  const int er = (lane >> 4) << 2, ec = lane & 15;
  const bool isv = n0 < 2048;
#pragma unroll
  for (int i = 0; i < 4; ++i) {
#pragma unroll
    for (int j = 0; j < 4; ++j) {
      int col = n0 + wn * 64 + j * 16 + ec;
      float bb = b_hid[col];
#pragma unroll
      for (int r = 0; r < 4; ++r) {
        int row = m0 + wm * 64 + i * 16 + er + r;
        float xv = silu_f(acc[i][j][r] + bb);
        if (isv)
          vv[(size_t)row * 2048 + col] = xv;
        else
          gate[(size_t)row * 2048 + (col - 2048)] = f2bf(xv);
      }
    }
  }
}

// ---------------- K7: MFMA out GEMM: accb_bf @ w_outT^T + b_out ------------
__global__ __launch_bounds__(256) void k_gemm_out_mfma(
    const unsigned short* __restrict__ A, const unsigned short* __restrict__ BT,
    const float* __restrict__ b_out, float* __restrict__ out) {
  __shared__ unsigned short Abuf[128 * 40];
  __shared__ unsigned short Bbuf[128 * 40];
  const int tid = threadIdx.x;
  const int lane = tid & 63, wave = tid >> 6;
  const int wm = wave >> 1, wn = wave & 1;
  const int m0 = blockIdx.y << 7, n0 = blockIdx.x << 7;
  const int K = 2048;
  f32x4 acc[4][4] = {};
  const int arow = tid >> 2, akq = (tid & 3) << 3;
  const int lr = lane & 15, lk = (lane >> 4) << 3;
  for (int k0 = 0; k0 < K; k0 += 32) {
    short8v va0 = *(const short8v*)&A[(size_t)(m0 + arow) * K + k0 + akq];
    short8v va1 = *(const short8v*)&A[(size_t)(m0 + arow + 64) * K + k0 + akq];
    short8v vb0 = *(const short8v*)&BT[(size_t)(n0 + arow) * K + k0 + akq];
    short8v vb1 = *(const short8v*)&BT[(size_t)(n0 + arow + 64) * K + k0 + akq];
    __syncthreads();
    *(short8v*)&Abuf[arow * 40 + akq] = va0;
    *(short8v*)&Abuf[(arow + 64) * 40 + akq] = va1;
    *(short8v*)&Bbuf[arow * 40 + akq] = vb0;
    *(short8v*)&Bbuf[(arow + 64) * 40 + akq] = vb1;
    __syncthreads();
    short8v af[4], bf[4];
#pragma unroll
    for (int i = 0; i < 4; ++i) {
      af[i] = *(const short8v*)&Abuf[(wm * 64 + i * 16 + lr) * 40 + lk];
      bf[i] = *(const short8v*)&Bbuf[(wn * 64 + i * 16 + lr) * 40 + lk];
    }
#pragma unroll
    for (int i = 0; i < 4; ++i)
#pragma unroll
      for (int j = 0; j < 4; ++j)
        acc[i][j] = __builtin_amdgcn_mfma_f32_16x16x32_bf16(af[i], bf[j],
                                                            acc[i][j], 0, 0, 0);
  }
  const int er = (lane >> 4) << 2, ec = lane & 15;
#pragma unroll
  for (int i = 0; i < 4; ++i) {
#pragma unroll
    for (int j = 0; j < 4; ++j) {
      int col = n0 + wn * 64 + j * 16 + ec;
      float bb = b_out[col];
#pragma unroll
      for (int r = 0; r < 4; ++r) {
        int row = m0 + wm * 64 + i * 16 + er + r;
        out[(size_t)row * 1024 + col] = acc[i][j][r] + bb;
      }
    }
  }
}

// ---------------- K4: qp = silu(q@w_q+b_q), kp = silu(k@w_k+b_k) -----------
__global__ __launch_bounds__(256) void k_proj(
    const float* __restrict__ q, const float* __restrict__ k,
    const float* __restrict__ w_q, const float* __restrict__ b_q,
    const float* __restrict__ w_k, const float* __restrict__ b_k,
    float* __restrict__ qp, float* __restrict__ kp) {
  __shared__ float As[16][68];
  __shared__ float Bs[16][132];
  const int tid = threadIdx.x;
  const int tx = tid & 15, ty = tid >> 4;
  const int m0 = blockIdx.x << 6;
  const bool isq = blockIdx.y == 0;
  const float* src = isq ? q : k;
  const float* w = isq ? w_q : w_k;
  const float* bv = isq ? b_q : b_k;
  float* dst = isq ? qp : kp;
  float acc[4][8] = {};
  for (int k0 = 0; k0 < 1024; k0 += 16) {
    {
      int row = tid >> 2, kq = (tid & 3) << 2;
      float4 x = *(const float4*)(src + (size_t)(m0 + row) * 1024 + k0 + kq);
      As[kq + 0][row] = x.x;
      As[kq + 1][row] = x.y;
      As[kq + 2][row] = x.z;
      As[kq + 3][row] = x.w;
    }
    int f = tid;
#pragma unroll
    for (int it = 0; it < 2; ++it, f += 256) {
      int kk = f >> 5, nq = (f & 31) << 2;
      *(float4*)&Bs[kk][nq] = *(const float4*)(w + (size_t)(k0 + kk) * 128 + nq);
    }
    __syncthreads();
#pragma unroll
    for (int kk = 0; kk < 16; ++kk) {
      float a[4], b[8];
      *(float4*)&a[0] = *(const float4*)&As[kk][ty << 2];
      *(float4*)&b[0] = *(const float4*)&Bs[kk][tx << 3];
      *(float4*)&b[4] = *(const float4*)&Bs[kk][(tx << 3) + 4];
#pragma unroll
      for (int i = 0; i < 4; ++i)
#pragma unroll
        for (int j = 0; j < 8; ++j) acc[i][j] = fmaf(a[i], b[j], acc[i][j]);
    }
    __syncthreads();
  }
#pragma unroll
  for (int i = 0; i < 4; ++i) {
    int r = m0 + (ty << 2) + i;
    float* drow = dst + (size_t)r * 128 + (tx << 3);
#pragma unroll
    for (int j = 0; j < 8; ++j) {
      float x = acc[i][j] + bv[(tx << 3) + j];
      drow[j] = silu_f(x);
    }
  }
}

// ---------------- K5: linkv split-K partials (NO atomics) ------------------
// grid (16 e-tiles, 8 splits, 4 b). partial[s][b][128][2048] fp32.
__global__ __launch_bounds__(256) void k_linkv(
    const float* __restrict__ kp, const float* __restrict__ vv,
    const float* __restrict__ ks_g, const float* __restrict__ ks_b,
    float* __restrict__ partial) {
  __shared__ float Ks[16][132];
  __shared__ float Vs[16][132];
  const int tid = threadIdx.x;
  const int tx = tid & 15, ty = tid >> 4;
  const int e0 = blockIdx.x << 7;
  const int nbase = blockIdx.z * 4096 + blockIdx.y * 512;
  float acc[8][8] = {};
  for (int n0 = 0; n0 < 512; n0 += 16) {
    int f = tid;
#pragma unroll
    for (int it = 0; it < 2; ++it, f += 256) {
      int nn = f >> 5, dq = (f & 31) << 2;
      float4 x = *(const float4*)(kp + (size_t)(nbase + n0 + nn) * 128 + dq);
      Ks[nn][dq + 0] = x.x * ks_g[128 + dq + 0] + ks_b[128 + dq + 0];
      Ks[nn][dq + 1] = x.y * ks_g[128 + dq + 1] + ks_b[128 + dq + 1];
      Ks[nn][dq + 2] = x.z * ks_g[128 + dq + 2] + ks_b[128 + dq + 2];
      Ks[nn][dq + 3] = x.w * ks_g[128 + dq + 3] + ks_b[128 + dq + 3];
    }
    f = tid;
#pragma unroll
    for (int it = 0; it < 2; ++it, f += 256) {
      int nn = f >> 5, eq = (f & 31) << 2;
      *(float4*)&Vs[nn][eq] =
          *(const float4*)(vv + (size_t)(nbase + n0 + nn) * 2048 + e0 + eq);
    }
    __syncthreads();
#pragma unroll
    for (int kk = 0; kk < 16; ++kk) {
      float a[8], b[8];
      *(float4*)&a[0] = *(const float4*)&Ks[kk][ty << 3];
      *(float4*)&a[4] = *(const float4*)&Ks[kk][(ty << 3) + 4];
      *(float4*)&b[0] = *(const float4*)&Vs[kk][tx << 3];
      *(float4*)&b[4] = *(const float4*)&Vs[kk][(tx << 3) + 4];
#pragma unroll
      for (int i = 0; i < 8; ++i)
#pragma unroll
        for (int j = 0; j < 8; ++j) acc[i][j] = fmaf(a[i], b[j], acc[i][j]);
    }
    __syncthreads();
  }
  // partial[s][b][d][e]: flat = (s*4 + b)*128*2048 + d*2048 + e
  float* base =
      partial + ((size_t)(blockIdx.y * 4 + blockIdx.z) * 128) * 2048;
#pragma unroll
  for (int i = 0; i < 8; ++i) {
    int d = (ty << 3) + i;
    float* drow = base + (size_t)d * 2048 + e0 + (tx << 3);
#pragma unroll
    for (int j = 0; j < 8; ++j) drow[j] = acc[i][j];
  }
}

// ---------------- K5b: linkv = sum_s partial[s] / 4096 ---------------------
__global__ __launch_bounds__(256) void k_linkv_reduce(
    const float* __restrict__ partial, float* __restrict__ linkv) {
  size_t o = ((size_t)blockIdx.x * 256 + threadIdx.x) * 4;  // float4 slot
  float4 s = *(const float4*)&partial[o];
#pragma unroll
  for (int sp = 1; sp < 8; ++sp) {
    float4 x = *(const float4*)&partial[o + (size_t)sp * 1048576];
    s.x += x.x;
    s.y += x.y;
    s.z += x.z;
    s.w += x.w;
  }
  const float inv = 1.f / 4096.f;
  s.x *= inv;
  s.y *= inv;
  s.z *= inv;
  s.w *= inv;
  *(float4*)&linkv[o] = s;
}

// ---------------- K6a: attn = relu(cq@ck^T/G + bias)^2 -> quad_attn --------
__global__ __launch_bounds__(256) void k_attn(
    const float* __restrict__ qp, const float* __restrict__ kp,
    const float* __restrict__ qs_g, const float* __restrict__ qs_b,
    const float* __restrict__ ks_g, const float* __restrict__ ks_b,
    const float* __restrict__ bias, float* __restrict__ qa) {
  __shared__ float Qs[16][132];
  __shared__ float Ksl[16][132];
  const int tid = threadIdx.x;
  const int tx = tid & 15, ty = tid >> 4;
  const int i0 = blockIdx.x << 7, j0 = blockIdx.y << 7;
  const int gbase = blockIdx.z << 8;
  float acc[8][8] = {};
  for (int d0 = 0; d0 < 128; d0 += 16) {
    int f = tid;
#pragma unroll
    for (int it = 0; it < 2; ++it, f += 256) {
      int row = f >> 2, dq = (f & 3) << 2;
      float4 x = *(const float4*)(qp + (size_t)(gbase + i0 + row) * 128 + d0 + dq);
      Qs[dq + 0][row] = x.x * qs_g[d0 + dq + 0] + qs_b[d0 + dq + 0];
      Qs[dq + 1][row] = x.y * qs_g[d0 + dq + 1] + qs_b[d0 + dq + 1];
      Qs[dq + 2][row] = x.z * qs_g[d0 + dq + 2] + qs_b[d0 + dq + 2];
      Qs[dq + 3][row] = x.w * qs_g[d0 + dq + 3] + qs_b[d0 + dq + 3];
      float4 y = *(const float4*)(kp + (size_t)(gbase + j0 + row) * 128 + d0 + dq);
      Ksl[dq + 0][row] = y.x * ks_g[d0 + dq + 0] + ks_b[d0 + dq + 0];
      Ksl[dq + 1][row] = y.y * ks_g[d0 + dq + 1] + ks_b[d0 + dq + 1];
      Ksl[dq + 2][row] = y.z * ks_g[d0 + dq + 2] + ks_b[d0 + dq + 2];
      Ksl[dq + 3][row] = y.w * ks_g[d0 + dq + 3] + ks_b[d0 + dq + 3];
    }
    __syncthreads();
#pragma unroll
    for (int kk = 0; kk < 16; ++kk) {
      float a[8], b[8];
      *(float4*)&a[0] = *(const float4*)&Qs[kk][ty << 3];
      *(float4*)&a[4] = *(const float4*)&Qs[kk][(ty << 3) + 4];
      *(float4*)&b[0] = *(const float4*)&Ksl[kk][tx << 3];
      *(float4*)&b[4] = *(const float4*)&Ksl[kk][(tx << 3) + 4];
#pragma unroll
      for (int i = 0; i < 8; ++i)
#pragma unroll
        for (int j = 0; j < 8; ++j) acc[i][j] = fmaf(a[i], b[j], acc[i][j]);
    }
    __syncthreads();
  }
#pragma unroll
  for (int i = 0; i < 8; ++i) {
    int gi = i0 + (ty << 3) + i;
    float* drow = qa + (size_t)(gbase + gi) * 256 + j0 + (tx << 3);
    const float* brow = bias + (size_t)gi * 256 + j0 + (tx << 3);
#pragma unroll
    for (int j = 0; j < 8; ++j) {
      float s = acc[i][j] * (1.f / 256.f) + brow[j];
      float r = fmaxf(s, 0.f);
      drow[j] = r * r;
    }
  }
}

// ---------------- K6b: accb_bf = bf16(gate_bf * (attn@cv + clq@lin_kv)) ----
__global__ __launch_bounds__(256) void k_combine(
    const float* __restrict__ qa, const float* __restrict__ vv,
    const float* __restrict__ qp, const float* __restrict__ qs_g,
    const float* __restrict__ qs_b, const float* __restrict__ linkv,
    const unsigned short* __restrict__ gate_bf,
    unsigned short* __restrict__ accb_bf) {
  __shared__ float As[16][132];
  __shared__ float Bs[16][132];
  const int tid = threadIdx.x;
  const int tx = tid & 15, ty = tid >> 4;
  const int e0 = blockIdx.x << 7;
  const int i0 = blockIdx.y << 7;
  const int gbase = blockIdx.z << 8;
  const int bb = blockIdx.z >> 4;
  float acc[8][8] = {};
  for (int j0 = 0; j0 < 256; j0 += 16) {
    int f = tid;
#pragma unroll
    for (int it = 0; it < 2; ++it, f += 256) {
      int row = f >> 2, jq = (f & 3) << 2;
      float4 x = *(const float4*)(qa + (size_t)(gbase + i0 + row) * 256 + j0 + jq);
      As[jq + 0][row] = x.x;
      As[jq + 1][row] = x.y;
      As[jq + 2][row] = x.z;
      As[jq + 3][row] = x.w;
    }
    f = tid;
#pragma unroll
    for (int it = 0; it < 2; ++it, f += 256) {
      int jj = f >> 5, eq = (f & 31) << 2;
      *(float4*)&Bs[jj][eq] =
          *(const float4*)(vv + (size_t)(gbase + j0 + jj) * 2048 + e0 + eq);
    }
    __syncthreads();
#pragma unroll
    for (int kk = 0; kk < 16; ++kk) {
      float a[8], b[8];
      *(float4*)&a[0] = *(const float4*)&As[kk][ty << 3];
      *(float4*)&a[4] = *(const float4*)&As[kk][(ty << 3) + 4];
      *(float4*)&b[0] = *(const float4*)&Bs[kk][tx << 3];
      *(float4*)&b[4] = *(const float4*)&Bs[kk][(tx << 3) + 4];
#pragma unroll
      for (int i = 0; i < 8; ++i)
#pragma unroll
        for (int j = 0; j < 8; ++j) acc[i][j] = fmaf(a[i], b[j], acc[i][j]);
    }
    __syncthreads();
  }
  for (int d0 = 0; d0 < 128; d0 += 16) {
    int f = tid;
#pragma unroll
    for (int it = 0; it < 2; ++it, f += 256) {
      int row = f >> 2, dq = (f & 3) << 2;
      float4 x = *(const float4*)(qp + (size_t)(gbase + i0 + row) * 128 + d0 + dq);
      As[dq + 0][row] = x.x * qs_g[128 + d0 + dq + 0] + qs_b[128 + d0 + dq + 0];
      As[dq + 1][row] = x.y * qs_g[128 + d0 + dq + 1] + qs_b[128 + d0 + dq + 1];
      As[dq + 2][row] = x.z * qs_g[128 + d0 + dq + 2] + qs_b[128 + d0 + dq + 2];
      As[dq + 3][row] = x.w * qs_g[128 + d0 + dq + 3] + qs_b[128 + d0 + dq + 3];
    }
    f = tid;
#pragma unroll
    for (int it = 0; it < 2; ++it, f += 256) {
      int dd = f >> 5, eq = (f & 31) << 2;
      *(float4*)&Bs[dd][eq] = *(const float4*)(
          linkv + ((size_t)bb * 128 + d0 + dd) * 2048 + e0 + eq);
    }
    __syncthreads();
#pragma unroll
    for (int kk = 0; kk < 16; ++kk) {
      float a[8], b[8];
      *(float4*)&a[0] = *(const float4*)&As[kk][ty << 3];
      *(float4*)&a[4] = *(const float4*)&As[kk][(ty << 3) + 4];
      *(float4*)&b[0] = *(const float4*)&Bs[kk][tx << 3];
      *(float4*)&b[4] = *(const float4*)&Bs[kk][(tx << 3) + 4];
#pragma unroll
      for (int i = 0; i < 8; ++i)
#pragma unroll
        for (int j = 0; j < 8; ++j) acc[i][j] = fmaf(a[i], b[j], acc[i][j]);
    }
    __syncthreads();
  }
#pragma unroll
  for (int i = 0; i < 8; ++i) {
    size_t r = (size_t)(gbase + i0 + (ty << 3) + i);
    const unsigned short* grow = gate_bf + r * 2048 + e0 + (tx << 3);
    unsigned short* arow = accb_bf + r * 2048 + e0 + (tx << 3);
#pragma unroll
    for (int j = 0; j < 8; ++j) arow[j] = f2bf(bf2f(grow[j]) * acc[i][j]);
  }
}

// ---------------------------------------------------------------------------
extern "C" void kernel_launch(void* const* d_in, const int* in_sizes, int n_in,
                              void* d_out, int out_size, void* d_ws,
                              size_t ws_size, hipStream_t stream) {
  const float* q = (const float*)d_in[0];
  const float* k = (const float*)d_in[1];
  const float* v = (const float*)d_in[2];
  const float* ln_g = (const float*)d_in[3];
  const float* ln_b = (const float*)d_in[4];
  const float* w_hid = (const float*)d_in[5];
  const float* b_hid = (const float*)d_in[6];
  const float* w_q = (const float*)d_in[7];
  const float* b_q = (const float*)d_in[8];
  const float* w_k = (const float*)d_in[9];
  const float* b_k = (const float*)d_in[10];
  const float* qs_g = (const float*)d_in[11];
  const float* qs_b = (const float*)d_in[12];
  const float* ks_g = (const float*)d_in[13];
  const float* ks_b = (const float*)d_in[14];
  const float* rel = (const float*)d_in[15];
  const float* w_out = (const float*)d_in[16];
  const float* b_out = (const float*)d_in[17];

  if (ws_size < (size_t)268435456) return;
  float* vv = (float*)d_ws;                                    // 134.2 MB
  unsigned short* gate_bf = (unsigned short*)(vv + (size_t)16384 * 2048);
  unsigned short* accb_bf = gate_bf + (size_t)16384 * 2048;    // ends 256 MiB
  // w_outT reuses the gate_bf region AFTER k_combine's last read of gate_bf.
  unsigned short* w_outT = gate_bf;  // 2048*1024 bf16 = 4 MiB

  float* out = (float*)d_out;                  // 16,777,216 floats
  float* qa = out + (size_t)16384 * 1024;      // output 2
  // scratch inside out region (all dead before k_gemm_out_mfma writes out):
  float* qp = out;                             // 2,097,152 f
  float* kp = qp + 2097152;                    // 2,097,152 f
  float* mean = kp + 2097152;                  // 16384
  float* rstd = mean + 16384;                  // 16384
  float* bias = rstd + 16384;                  // 65536
  float* linkv = bias + 65536;                 // 1,048,576 -> ends 5,341,184
  unsigned short* lnv = (unsigned short*)(linkv + 1048576);  // 16,777,216 bf16
  unsigned short* w_hidT = (unsigned short*)(out + 13729792);  // 4,194,304 bf16
  // linkv partials reuse the lnv region (dead after k_gemm_hid_mfma):
  // [8][4][128][2048] fp32 = 8,388,608 floats -> exactly lnv's span.
  float* linkv_part = (float*)lnv;

  k_ln_stats<<<4096, 256, 0, stream>>>(v, mean, rstd);
  k_bias<<<256, 256, 0, stream>>>(rel, bias);
  k_cvt_lnv<<<8192, 256, 0, stream>>>(v, mean, rstd, ln_g, ln_b, lnv);
  k_transpose_cvt<<<dim3(128, 32), 256, 0, stream>>>(w_hid, w_hidT, 1024, 4096);
  k_gemm_hid_mfma<<<dim3(32, 128), 256, 0, stream>>>(lnv, w_hidT, b_hid, vv,
                                                     gate_bf);
  k_proj<<<dim3(256, 2), 256, 0, stream>>>(q, k, w_q, b_q, w_k, b_k, qp, kp);
  k_linkv<<<dim3(16, 8, 4), 256, 0, stream>>>(kp, vv, ks_g, ks_b, linkv_part);
  k_linkv_reduce<<<1024, 256, 0, stream>>>(linkv_part, linkv);
  k_attn<<<dim3(2, 2, 64), 256, 0, stream>>>(qp, kp, qs_g, qs_b, ks_g, ks_b,
                                             bias, qa);
  k_combine<<<dim3(16, 2, 64), 256, 0, stream>>>(qa, vv, qp, qs_g, qs_b, linkv,
                                                 gate_bf, accb_bf);
  // transpose w_out into the (now-dead) gate_bf region, then final GEMM.
  k_transpose_cvt<<<dim3(32, 64), 256, 0, stream>>>(w_out, w_outT, 2048, 1024);
  k_gemm_out_mfma<<<dim3(8, 128), 256, 0, stream>>>(accb_bf, w_outT, b_out,
                                                    out);
}